// Round 1
// baseline (584.951 us; speedup 1.0000x reference)
//
#include <hip/hip_runtime.h>

#define M_TOK 8192
#define N_OUT 4096
#define K_IN  4096
#define NT    (K_IN / 64)                    // 64 K-tiles of BK=64
#define CVT_BLOCKS ((M_TOK * K_IN) / 2048)   // 16384: 256 thr * 8 f32 each
#define DEQ_BLOCKS (N_OUT * 4 / 4)           // 4096: 4 waves/block, 1 group/wave

typedef __bf16 bf16x8 __attribute__((ext_vector_type(8)));
typedef float f32x4 __attribute__((ext_vector_type(4)));

__device__ __forceinline__ unsigned short f2b(float f) {
  union { float f; unsigned u; } c; c.f = f;
  unsigned u = c.u;
  return (unsigned short)((u + 0x7FFFu + ((u >> 16) & 1u)) >> 16);  // RNE
}

// ---------------- kernel 1: fused x-cast + W dequant/FWHT (unchanged) ----------------
__global__ __launch_bounds__(256) void prep_kernel(const float* __restrict__ x,
                                                   unsigned short* __restrict__ xb,
                                                   const int* __restrict__ codes,
                                                   const float* __restrict__ grid,
                                                   const float* __restrict__ scales,
                                                   unsigned short* __restrict__ Wt) {
  if (blockIdx.x < CVT_BLOCKS) {
    long i = ((long)blockIdx.x * 256 + threadIdx.x) * 8;
    float4 a = *(const float4*)(x + i);
    float4 b = *(const float4*)(x + i + 4);
    union { unsigned short us[8]; uint4 v; } o;
    o.us[0] = f2b(a.x); o.us[1] = f2b(a.y); o.us[2] = f2b(a.z); o.us[3] = f2b(a.w);
    o.us[4] = f2b(b.x); o.us[5] = f2b(b.y); o.us[6] = f2b(b.z); o.us[7] = f2b(b.w);
    *(uint4*)(xb + i) = o.v;
  } else {
    int bid = blockIdx.x - CVT_BLOCKS;
    int wave = threadIdx.x >> 6;
    int lane = threadIdx.x & 63;
    int G = bid * 4 + wave;
    int o = G >> 2;
    int g = G & 3;
    const int* crow = codes + (long)o * 2048 + g * 512 + lane * 8;
    int4 c0 = *(const int4*)crow;
    int4 c1 = *(const int4*)(crow + 4);
    float v[16];
    const float2* g2p = (const float2*)grid;
    float2 t;
    t = g2p[c0.x]; v[0] = t.x;  v[1] = t.y;
    t = g2p[c0.y]; v[2] = t.x;  v[3] = t.y;
    t = g2p[c0.z]; v[4] = t.x;  v[5] = t.y;
    t = g2p[c0.w]; v[6] = t.x;  v[7] = t.y;
    t = g2p[c1.x]; v[8] = t.x;  v[9] = t.y;
    t = g2p[c1.y]; v[10] = t.x; v[11] = t.y;
    t = g2p[c1.z]; v[12] = t.x; v[13] = t.y;
    t = g2p[c1.w]; v[14] = t.x; v[15] = t.y;
#pragma unroll
    for (int s = 1; s < 16; s <<= 1) {
#pragma unroll
      for (int base = 0; base < 16; base++) {
        if (!(base & s)) {
          float a = v[base], b = v[base | s];
          v[base] = a + b;
          v[base | s] = a - b;
        }
      }
    }
#pragma unroll
    for (int m = 1; m <= 32; m <<= 1) {
      bool hi = (lane & m) != 0;
#pragma unroll
      for (int c = 0; c < 16; c++) {
        float p = __shfl_xor(v[c], m, 64);
        v[c] = hi ? p - v[c] : p + v[c];
      }
    }
    float sc = scales[o * 4 + g] * 0.03125f;
    union { unsigned short us[16]; uint4 q[2]; } out;
#pragma unroll
    for (int c = 0; c < 16; c++) out.us[c] = f2b(v[c] * sc);
    unsigned short* wp = Wt + (long)o * 4096 + g * 1024 + lane * 16;
    *(uint4*)wp = out.q[0];
    *(uint4*)(wp + 8) = out.q[1];
  }
}

// ---------------- kernel 2: 256x256-tile 8-phase bf16 GEMM, C = A * B^T + bias ----------------
// 8 waves (2M x 4N), per-wave output 128x64. BK=64, LDS = 2 buf x (A 32KB + B 32KB) = 128 KiB.
// LDS layout per tile: 2048 granules of 16B. Granule g holds global chunk ((g&7) ^ ((g>>3)&7))
// of row (g>>3)  -> fragment ds_read_b128 of 16 rows hits all 8 bank slots (XOR swizzle, T2).
// Stage: thread tid covers granules tid + j*512 via global_load_lds(16B), linear LDS dest,
// inverse-swizzled global source (both-sides-or-neither rule).
// Pipeline: at top of tile t, issue all 8 loads of tile t+1 (buffer t-1 read retired at the
// preceding barrier), then s_waitcnt vmcnt(8) -> tile t landed, t+1 stays in flight (T4,
// never vmcnt(0) in main loop). 4 phases/tile, 16 MFMA each, setprio around MFMA (T5),
// raw s_barrier + sched_barrier(0) pins (T3 lockstep).
__device__ __forceinline__ void load16_to_lds(const unsigned short* g, unsigned short* l) {
  __builtin_amdgcn_global_load_lds((const __attribute__((address_space(1))) void*)g,
                                   (__attribute__((address_space(3))) void*)l,
                                   16, 0, 0);
}

__device__ __forceinline__ void phase_barrier() {
  __builtin_amdgcn_s_barrier();
  __builtin_amdgcn_sched_barrier(0);
}

__global__ __launch_bounds__(512, 2) void gemm_kernel(const unsigned short* __restrict__ A,
                                                      const unsigned short* __restrict__ B,
                                                      const float* __restrict__ bias,
                                                      float* __restrict__ C) {
  __shared__ unsigned short sA[2][256 * 64];
  __shared__ unsigned short sB[2][256 * 64];

  // XCD-chunked bijective swizzle: 512 wgs, 8 XCDs -> each XCD a contiguous 64-wg chunk.
  const int wg  = blockIdx.x;
  const int swz = (wg & 7) * (512 / 8) + (wg >> 3);
  const int bn  = (swz & 15) * 256;   // 16 N-tiles
  const int bm  = (swz >> 4) * 256;   // 32 M-tiles

  const int tid  = threadIdx.x;
  const int wave = tid >> 6;
  const int lane = tid & 63;
  const int wm   = wave >> 2;         // 0..1  (M half)
  const int wn   = wave & 3;          // 0..3  (N quarter)

  // ---- staging addresses: thread covers granules tid + j*512 for A and B ----
  const long K = K_IN;
  const unsigned short* aSrc[4];
  const unsigned short* bSrc[4];
  unsigned short* aDst[4];
  unsigned short* bDst[4];
#pragma unroll
  for (int j = 0; j < 4; j++) {
    const int g   = tid + j * 512;
    const int row = g >> 3;
    const int cg  = (g & 7) ^ (row & 7);          // inverse-swizzled global chunk
    aSrc[j] = A + (long)(bm + row) * K + cg * 8;
    bSrc[j] = B + (long)(bn + row) * K + cg * 8;
    aDst[j] = &sA[0][g * 8];
    bDst[j] = &sB[0][g * 8];
  }

  // ---- fragment read offsets (ushort elements), granule-XOR applied ----
  const int m7  = lane & 7;
  const int cb  = lane >> 4;                       // k-chunk base 0..3
  const int r0a = wm * 128 + (lane & 15);
  const int r0b = wn * 64  + (lane & 15);
  const int aoff0 = (r0a * 8 + ( cb      ^ m7)) * 8;   // kk=0
  const int aoff1 = (r0a * 8 + ((cb | 4) ^ m7)) * 8;   // kk=1
  const int boff0 = (r0b * 8 + ( cb      ^ m7)) * 8;
  const int boff1 = (r0b * 8 + ((cb | 4) ^ m7)) * 8;

  f32x4 acc[8][4] = {};

  // prologue: stage tile 0 into buffer 0
#pragma unroll
  for (int j = 0; j < 4; j++) {
    load16_to_lds(aSrc[j], aDst[j]);
    load16_to_lds(bSrc[j], bDst[j]);
  }

  for (int t = 0; t < NT; t++) {
    const int p = t & 1;
    const unsigned short* bufA = &sA[p][0];
    const unsigned short* bufB = &sB[p][0];

    // issue next tile's stages into the other buffer (its readers retired at the
    // barrier that ended tile t-1), then counted wait: tile t landed, t+1 in flight.
    if (t + 1 < NT) {
      const int koff = (t + 1) * 64;
      const int q16  = ((t + 1) & 1) * 16384;
#pragma unroll
      for (int j = 0; j < 4; j++) {
        load16_to_lds(aSrc[j] + koff, aDst[j] + q16);
        load16_to_lds(bSrc[j] + koff, bDst[j] + q16);
      }
      asm volatile("s_waitcnt vmcnt(8)" ::: "memory");
    } else {
      asm volatile("s_waitcnt vmcnt(0)" ::: "memory");
    }
    phase_barrier();   // all waves' tile-t stages landed

    bf16x8 a0[4], a1[4], b0[4];

    // ---- phase 0: kk=0, mi 0-3 (+ B kk0) ----
#pragma unroll
    for (int i = 0; i < 4; i++) b0[i] = *(const bf16x8*)(bufB + boff0 + i * 1024);
#pragma unroll
    for (int i = 0; i < 4; i++) a0[i] = *(const bf16x8*)(bufA + aoff0 + i * 1024);
    phase_barrier();
    __builtin_amdgcn_s_setprio(1);
#pragma unroll
    for (int mi = 0; mi < 4; mi++)
#pragma unroll
      for (int ni = 0; ni < 4; ni++)
        acc[mi][ni] = __builtin_amdgcn_mfma_f32_16x16x32_bf16(a0[mi], b0[ni], acc[mi][ni], 0, 0, 0);
    __builtin_amdgcn_s_setprio(0);
    phase_barrier();

    // ---- phase 1: kk=0, mi 4-7 ----
#pragma unroll
    for (int i = 0; i < 4; i++) a1[i] = *(const bf16x8*)(bufA + aoff0 + 4096 + i * 1024);
    phase_barrier();
    __builtin_amdgcn_s_setprio(1);
#pragma unroll
    for (int mi = 0; mi < 4; mi++)
#pragma unroll
      for (int ni = 0; ni < 4; ni++)
        acc[4 + mi][ni] = __builtin_amdgcn_mfma_f32_16x16x32_bf16(a1[mi], b0[ni], acc[4 + mi][ni], 0, 0, 0);
    __builtin_amdgcn_s_setprio(0);
    phase_barrier();

    // ---- phase 2: kk=1, mi 0-3 (+ B kk1) ----
#pragma unroll
    for (int i = 0; i < 4; i++) b0[i] = *(const bf16x8*)(bufB + boff1 + i * 1024);
#pragma unroll
    for (int i = 0; i < 4; i++) a0[i] = *(const bf16x8*)(bufA + aoff1 + i * 1024);
    phase_barrier();
    __builtin_amdgcn_s_setprio(1);
#pragma unroll
    for (int mi = 0; mi < 4; mi++)
#pragma unroll
      for (int ni = 0; ni < 4; ni++)
        acc[mi][ni] = __builtin_amdgcn_mfma_f32_16x16x32_bf16(a0[mi], b0[ni], acc[mi][ni], 0, 0, 0);
    __builtin_amdgcn_s_setprio(0);
    phase_barrier();

    // ---- phase 3: kk=1, mi 4-7 ----
#pragma unroll
    for (int i = 0; i < 4; i++) a1[i] = *(const bf16x8*)(bufA + aoff1 + 4096 + i * 1024);
    phase_barrier();
    __builtin_amdgcn_s_setprio(1);
#pragma unroll
    for (int mi = 0; mi < 4; mi++)
#pragma unroll
      for (int ni = 0; ni < 4; ni++)
        acc[4 + mi][ni] = __builtin_amdgcn_mfma_f32_16x16x32_bf16(a1[mi], b0[ni], acc[4 + mi][ni], 0, 0, 0);
    __builtin_amdgcn_s_setprio(0);
    phase_barrier();   // tile boundary: buffer p free for overwrite next iteration
  }

  // ---- epilogue: D[m=(lane>>4)*4+r][n=lane&15] per 16x16 tile ----
  const int cn  = lane & 15;
  const int cm4 = (lane >> 4) * 4;
#pragma unroll
  for (int ni = 0; ni < 4; ni++) {
    const int col = bn + wn * 64 + ni * 16 + cn;
    const float bb = bias[col];
#pragma unroll
    for (int mi = 0; mi < 8; mi++) {
#pragma unroll
      for (int r = 0; r < 4; r++) {
        const int row = bm + wm * 128 + mi * 16 + cm4 + r;
        C[(long)row * N_OUT + col] = acc[mi][ni][r] + bb;
      }
    }
  }
}

extern "C" void kernel_launch(void* const* d_in, const int* in_sizes, int n_in,
                              void* d_out, int out_size, void* d_ws, size_t ws_size,
                              hipStream_t stream) {
  const float* x      = (const float*)d_in[0];
  const int*   codes  = (const int*)d_in[1];
  const float* grid   = (const float*)d_in[2];
  const float* scales = (const float*)d_in[3];
  const float* bias   = (const float*)d_in[4];
  float* out = (float*)d_out;

  unsigned short* xb = (unsigned short*)d_ws;                    // 64 MiB bf16
  unsigned short* Wt = xb + (size_t)M_TOK * K_IN;                // 32 MiB bf16

  prep_kernel<<<CVT_BLOCKS + DEQ_BLOCKS, 256, 0, stream>>>(x, xb, codes, grid, scales, Wt);
  gemm_kernel<<<512, 512, 0, stream>>>(xb, Wt, bias, out);
}

// Round 3
// 546.624 us; speedup vs baseline: 1.0701x; 1.0701x over previous
//
#include <hip/hip_runtime.h>

#define M_TOK 8192
#define N_OUT 4096
#define K_IN  4096
#define NT    (K_IN / 64)                    // 64 K-tiles of BK=64
#define CVT_BLOCKS ((M_TOK * K_IN) / 2048)   // 16384: 256 thr * 8 f32 each
#define DEQ_BLOCKS (N_OUT * 4 / 4)           // 4096: 4 waves/block, 1 group/wave

typedef __bf16 bf16x8 __attribute__((ext_vector_type(8)));
typedef float f32x4 __attribute__((ext_vector_type(4)));

__device__ __forceinline__ unsigned short f2b(float f) {
  union { float f; unsigned u; } c; c.f = f;
  unsigned u = c.u;
  return (unsigned short)((u + 0x7FFFu + ((u >> 16) & 1u)) >> 16);  // RNE
}

// ---------------- kernel 1: fused x-cast + W dequant/FWHT (unchanged) ----------------
__global__ __launch_bounds__(256) void prep_kernel(const float* __restrict__ x,
                                                   unsigned short* __restrict__ xb,
                                                   const int* __restrict__ codes,
                                                   const float* __restrict__ grid,
                                                   const float* __restrict__ scales,
                                                   unsigned short* __restrict__ Wt) {
  if (blockIdx.x < CVT_BLOCKS) {
    long i = ((long)blockIdx.x * 256 + threadIdx.x) * 8;
    float4 a = *(const float4*)(x + i);
    float4 b = *(const float4*)(x + i + 4);
    union { unsigned short us[8]; uint4 v; } o;
    o.us[0] = f2b(a.x); o.us[1] = f2b(a.y); o.us[2] = f2b(a.z); o.us[3] = f2b(a.w);
    o.us[4] = f2b(b.x); o.us[5] = f2b(b.y); o.us[6] = f2b(b.z); o.us[7] = f2b(b.w);
    *(uint4*)(xb + i) = o.v;
  } else {
    int bid = blockIdx.x - CVT_BLOCKS;
    int wave = threadIdx.x >> 6;
    int lane = threadIdx.x & 63;
    int G = bid * 4 + wave;
    int o = G >> 2;
    int g = G & 3;
    const int* crow = codes + (long)o * 2048 + g * 512 + lane * 8;
    int4 c0 = *(const int4*)crow;
    int4 c1 = *(const int4*)(crow + 4);
    float v[16];
    const float2* g2p = (const float2*)grid;
    float2 t;
    t = g2p[c0.x]; v[0] = t.x;  v[1] = t.y;
    t = g2p[c0.y]; v[2] = t.x;  v[3] = t.y;
    t = g2p[c0.z]; v[4] = t.x;  v[5] = t.y;
    t = g2p[c0.w]; v[6] = t.x;  v[7] = t.y;
    t = g2p[c1.x]; v[8] = t.x;  v[9] = t.y;
    t = g2p[c1.y]; v[10] = t.x; v[11] = t.y;
    t = g2p[c1.z]; v[12] = t.x; v[13] = t.y;
    t = g2p[c1.w]; v[14] = t.x; v[15] = t.y;
#pragma unroll
    for (int s = 1; s < 16; s <<= 1) {
#pragma unroll
      for (int base = 0; base < 16; base++) {
        if (!(base & s)) {
          float a = v[base], b = v[base | s];
          v[base] = a + b;
          v[base | s] = a - b;
        }
      }
    }
#pragma unroll
    for (int m = 1; m <= 32; m <<= 1) {
      bool hi = (lane & m) != 0;
#pragma unroll
      for (int c = 0; c < 16; c++) {
        float p = __shfl_xor(v[c], m, 64);
        v[c] = hi ? p - v[c] : p + v[c];
      }
    }
    float sc = scales[o * 4 + g] * 0.03125f;
    union { unsigned short us[16]; uint4 q[2]; } out;
#pragma unroll
    for (int c = 0; c < 16; c++) out.us[c] = f2b(v[c] * sc);
    unsigned short* wp = Wt + (long)o * 4096 + g * 1024 + lane * 16;
    *(uint4*)wp = out.q[0];
    *(uint4*)(wp + 8) = out.q[1];
  }
}

// ---------------- kernel 2: 256x256-tile 4-phase bf16 GEMM, C = A * B^T + bias ----------------
// 8 waves (2M x 4N), per-wave output 128x64. BK=64, LDS = 2 buf x (A 32KB + B 32KB) = 128 KiB.
// Granule XOR swizzle (T2): granule g holds global chunk ((g&7)^((g>>3)&7)) of row g>>3;
// linear LDS dest + inverse-swizzled global source + swizzled ds_read (both-sides rule).
// Staging group j = rows [j*64, j*64+63] (aSrc[j]/bSrc[j], 2 granule-loads per thread... 1 each).
// Read deadlines for tile T: {b0..b3, a0, a2} at T.P0;  {a1, a3} at T.P1.
// DEADLINE-ORDERED issue during tile T-1:  P0: b0,b1 | P1: b2,b3 | P2: a0,a2 | P3: a1,a3.
// Waits (per-wave, in-order vmcnt accounting; each precedes a barrier -> global guarantee):
//   W1 after P3 MFMA: vmcnt(2)  -> all of T+1 except its newest pair (a1,a3) landed.
//   W2 after P0 MFMA: vmcnt(2)  -> current tile's a1,a3 landed (newest-2 = next tile's b0,b1);
//                     vmcnt(0) on the final tile (nothing else in flight).
// Never drains to 0 in steady state (T4); setprio around MFMA clusters (T5).
__device__ __forceinline__ void load16_to_lds(const unsigned short* g, unsigned short* l) {
  __builtin_amdgcn_global_load_lds((const __attribute__((address_space(1))) void*)g,
                                   (__attribute__((address_space(3))) void*)l,
                                   16, 0, 0);
}

__device__ __forceinline__ void phase_barrier() {
  __builtin_amdgcn_s_barrier();
  __builtin_amdgcn_sched_barrier(0);
}

__global__ __launch_bounds__(512, 2) void gemm_kernel(const unsigned short* __restrict__ A,
                                                      const unsigned short* __restrict__ B,
                                                      const float* __restrict__ bias,
                                                      float* __restrict__ C) {
  __shared__ unsigned short sA[2][256 * 64];
  __shared__ unsigned short sB[2][256 * 64];

  // XCD-chunked bijective swizzle: 512 wgs, 8 XCDs -> each XCD a contiguous 64-wg chunk.
  const int wg  = blockIdx.x;
  const int swz = (wg & 7) * (512 / 8) + (wg >> 3);
  const int bn  = (swz & 15) * 256;   // 16 N-tiles
  const int bm  = (swz >> 4) * 256;   // 32 M-tiles

  const int tid  = threadIdx.x;
  const int wave = tid >> 6;
  const int lane = tid & 63;
  const int wm   = wave >> 2;         // 0..1  (M half)
  const int wn   = wave & 3;          // 0..3  (N quarter)

  // ---- staging addresses: thread covers granule tid + j*512 (group j = rows j*64..j*64+63) ----
  const long K = K_IN;
  const unsigned short* aSrc[4];
  const unsigned short* bSrc[4];
  unsigned short* aDst[4];
  unsigned short* bDst[4];
#pragma unroll
  for (int j = 0; j < 4; j++) {
    const int g   = tid + j * 512;
    const int row = g >> 3;
    const int cg  = (g & 7) ^ (row & 7);          // inverse-swizzled global chunk
    aSrc[j] = A + (long)(bm + row) * K + cg * 8;
    bSrc[j] = B + (long)(bn + row) * K + cg * 8;
    aDst[j] = &sA[0][g * 8];
    bDst[j] = &sB[0][g * 8];
  }

  // ---- fragment read offsets (ushort elements), granule-XOR applied ----
  const int m7  = lane & 7;
  const int cb  = lane >> 4;                       // k-chunk base 0..3
  const int r0a = wm * 128 + (lane & 15);
  const int r0b = wn * 64  + (lane & 15);
  const int aoff0 = (r0a * 8 + ( cb      ^ m7)) * 8;   // kk=0
  const int aoff1 = (r0a * 8 + ((cb | 4) ^ m7)) * 8;   // kk=1
  const int boff0 = (r0b * 8 + ( cb      ^ m7)) * 8;
  const int boff1 = (r0b * 8 + ((cb | 4) ^ m7)) * 8;

  f32x4 acc[8][4] = {};

  // ---- prologue: stage tile 0 in deadline order; leave a1,a3 in flight ----
  load16_to_lds(bSrc[0], bDst[0]);
  load16_to_lds(bSrc[1], bDst[1]);
  load16_to_lds(bSrc[2], bDst[2]);
  load16_to_lds(bSrc[3], bDst[3]);
  load16_to_lds(aSrc[0], aDst[0]);
  load16_to_lds(aSrc[2], aDst[2]);
  load16_to_lds(aSrc[1], aDst[1]);
  load16_to_lds(aSrc[3], aDst[3]);
  asm volatile("s_waitcnt vmcnt(2)" ::: "memory");
  phase_barrier();

  for (int t = 0; t < NT; t++) {
    const int p = t & 1;
    const unsigned short* bufA = &sA[p][0];
    const unsigned short* bufB = &sB[p][0];
    const bool pf   = (t + 1 < NT);
    const int  koff = (t + 1) * 64;
    const int  q16  = (p ^ 1) * 16384;

    bf16x8 a0[4], a1[4], b0[4];

    // ---- phase 0: kk=0, mi 0-3 | issue b0,b1 of t+1 | W2 guards this tile's a1,a3 ----
#pragma unroll
    for (int i = 0; i < 4; i++) b0[i] = *(const bf16x8*)(bufB + boff0 + i * 1024);
#pragma unroll
    for (int i = 0; i < 4; i++) a0[i] = *(const bf16x8*)(bufA + aoff0 + i * 1024);
    if (pf) {
      load16_to_lds(bSrc[0] + koff, bDst[0] + q16);
      load16_to_lds(bSrc[1] + koff, bDst[1] + q16);
    }
    phase_barrier();
    __builtin_amdgcn_s_setprio(1);
#pragma unroll
    for (int mi = 0; mi < 4; mi++)
#pragma unroll
      for (int ni = 0; ni < 4; ni++)
        acc[mi][ni] = __builtin_amdgcn_mfma_f32_16x16x32_bf16(a0[mi], b0[ni], acc[mi][ni], 0, 0, 0);
    __builtin_amdgcn_s_setprio(0);
    if (pf) asm volatile("s_waitcnt vmcnt(2)" ::: "memory");   // a1,a3(t) landed
    else    asm volatile("s_waitcnt vmcnt(0)" ::: "memory");   // final tile: drain
    phase_barrier();

    // ---- phase 1: kk=0, mi 4-7 | issue b2,b3 ----
#pragma unroll
    for (int i = 0; i < 4; i++) a1[i] = *(const bf16x8*)(bufA + aoff0 + 4096 + i * 1024);
    if (pf) {
      load16_to_lds(bSrc[2] + koff, bDst[2] + q16);
      load16_to_lds(bSrc[3] + koff, bDst[3] + q16);
    }
    phase_barrier();
    __builtin_amdgcn_s_setprio(1);
#pragma unroll
    for (int mi = 0; mi < 4; mi++)
#pragma unroll
      for (int ni = 0; ni < 4; ni++)
        acc[4 + mi][ni] = __builtin_amdgcn_mfma_f32_16x16x32_bf16(a1[mi], b0[ni], acc[4 + mi][ni], 0, 0, 0);
    __builtin_amdgcn_s_setprio(0);
    phase_barrier();

    // ---- phase 2: kk=1, mi 0-3 | issue a0,a2 ----
#pragma unroll
    for (int i = 0; i < 4; i++) b0[i] = *(const bf16x8*)(bufB + boff1 + i * 1024);
#pragma unroll
    for (int i = 0; i < 4; i++) a0[i] = *(const bf16x8*)(bufA + aoff1 + i * 1024);
    if (pf) {
      load16_to_lds(aSrc[0] + koff, aDst[0] + q16);
      load16_to_lds(aSrc[2] + koff, aDst[2] + q16);
    }
    phase_barrier();
    __builtin_amdgcn_s_setprio(1);
#pragma unroll
    for (int mi = 0; mi < 4; mi++)
#pragma unroll
      for (int ni = 0; ni < 4; ni++)
        acc[mi][ni] = __builtin_amdgcn_mfma_f32_16x16x32_bf16(a0[mi], b0[ni], acc[mi][ni], 0, 0, 0);
    __builtin_amdgcn_s_setprio(0);
    phase_barrier();

    // ---- phase 3: kk=1, mi 4-7 | issue a1,a3 | W1 guards t+1's P0 reads ----
#pragma unroll
    for (int i = 0; i < 4; i++) a1[i] = *(const bf16x8*)(bufA + aoff1 + 4096 + i * 1024);
    if (pf) {
      load16_to_lds(aSrc[1] + koff, aDst[1] + q16);
      load16_to_lds(aSrc[3] + koff, aDst[3] + q16);
    }
    phase_barrier();
    __builtin_amdgcn_s_setprio(1);
#pragma unroll
    for (int mi = 0; mi < 4; mi++)
#pragma unroll
      for (int ni = 0; ni < 4; ni++)
        acc[4 + mi][ni] = __builtin_amdgcn_mfma_f32_16x16x32_bf16(a1[mi], b0[ni], acc[4 + mi][ni], 0, 0, 0);
    __builtin_amdgcn_s_setprio(0);
    if (pf) asm volatile("s_waitcnt vmcnt(2)" ::: "memory");   // t+1: all but a1,a3 landed
    phase_barrier();   // buffer p free for overwrite next iteration
  }

  // ---- epilogue: D[m=(lane>>4)*4+r][n=lane&15] per 16x16 tile ----
  const int cn  = lane & 15;
  const int cm4 = (lane >> 4) * 4;
#pragma unroll
  for (int ni = 0; ni < 4; ni++) {
    const int col = bn + wn * 64 + ni * 16 + cn;
    const float bb = bias[col];
#pragma unroll
    for (int mi = 0; mi < 8; mi++) {
#pragma unroll
      for (int r = 0; r < 4; r++) {
        const int row = bm + wm * 128 + mi * 16 + cm4 + r;
        C[(long)row * N_OUT + col] = acc[mi][ni][r] + bb;
      }
    }
  }
}

extern "C" void kernel_launch(void* const* d_in, const int* in_sizes, int n_in,
                              void* d_out, int out_size, void* d_ws, size_t ws_size,
                              hipStream_t stream) {
  const float* x      = (const float*)d_in[0];
  const int*   codes  = (const int*)d_in[1];
  const float* grid   = (const float*)d_in[2];
  const float* scales = (const float*)d_in[3];
  const float* bias   = (const float*)d_in[4];
  float* out = (float*)d_out;

  unsigned short* xb = (unsigned short*)d_ws;                    // 64 MiB bf16
  unsigned short* Wt = xb + (size_t)M_TOK * K_IN;                // 32 MiB bf16

  prep_kernel<<<CVT_BLOCKS + DEQ_BLOCKS, 256, 0, stream>>>(x, xb, codes, grid, scales, Wt);
  gemm_kernel<<<512, 512, 0, stream>>>(xb, Wt, bias, out);
}